// Round 8
// baseline (117.822 us; speedup 1.0000x reference)
//
#include <hip/hip_runtime.h>
#include <hip/hip_bf16.h>

#define NB 4096
#define DK 1024           // elements per row (fp8 row = 1024 B)
#define EPSF 1e-6f
#define QSCALE 16.0f      // fp8 pre-scale (power of 2; cancelled exactly in exp)

typedef __attribute__((ext_vector_type(8))) int   i32x8_t;
typedef __attribute__((ext_vector_type(4))) int   i32x4_t;
typedef __attribute__((ext_vector_type(4))) float f32x4_t;

// ---------------------------------------------------------------------------
// Fragment-swizzled fp8 layout (both matrices): for row, k:
//   p = row>>4, r = row&15, kb = k>>7, q = (k>>5)&3, b = k&31
//   byte offset = (p*32 + kb*4 + q)*512 + r*32 + b
// A wave's MFMA fragment (lane = q*16 + l15) for panel p, k-block kb is
// 64 lanes x 32 contiguous bytes at (p*32+kb*4+q)*512 + l15*32 — two
// coalesced global_load_dwordx4 per fragment. Bytes identical to the r5 LDS
// fragments (absmax-0 proven).
// ---------------------------------------------------------------------------

// ---------------------------------------------------------------------------
// Kernel 1: wave-per-row normalize of x and y -> fp8 e4m3 (x QSCALE) written
// in fragment-swizzled layout, plus exact fp32 diagonal cos-sim. Also zeroes
// rowsum/colsum.
// ---------------------------------------------------------------------------
__global__ __launch_bounds__(256) void normalize_rows(
    const float* __restrict__ x, const float* __restrict__ y,
    unsigned* __restrict__ xq, unsigned* __restrict__ yq,
    float* __restrict__ sdiag, float* __restrict__ zerobuf)
{
    const int t = threadIdx.x;
    const int gid = blockIdx.x * 256 + t;
    if (gid < 2 * NB) zerobuf[gid] = 0.f;   // rowsum+colsum contiguous

    const int wave = t >> 6;
    const int lane = t & 63;
    const int row  = blockIdx.x * 4 + wave;

    const float4* xr = reinterpret_cast<const float4*>(x + (size_t)row * DK);
    const float4* yr = reinterpret_cast<const float4*>(y + (size_t)row * DK);

    float4 xv[4], yv[4];
    float ssx = 0.f, ssy = 0.f, sxy = 0.f;
    #pragma unroll
    for (int j = 0; j < 4; ++j) {
        xv[j] = xr[j * 64 + lane];
        yv[j] = yr[j * 64 + lane];
        ssx += xv[j].x*xv[j].x + xv[j].y*xv[j].y + xv[j].z*xv[j].z + xv[j].w*xv[j].w;
        ssy += yv[j].x*yv[j].x + yv[j].y*yv[j].y + yv[j].z*yv[j].z + yv[j].w*yv[j].w;
        sxy += xv[j].x*yv[j].x + xv[j].y*yv[j].y + xv[j].z*yv[j].z + xv[j].w*yv[j].w;
    }
    #pragma unroll
    for (int off = 1; off < 64; off <<= 1) {
        ssx += __shfl_xor(ssx, off, 64);
        ssy += __shfl_xor(ssy, off, 64);
        sxy += __shfl_xor(sxy, off, 64);
    }
    const float invx = 1.0f / fmaxf(sqrtf(ssx), EPSF);
    const float invy = 1.0f / fmaxf(sqrtf(ssy), EPSF);
    const float sx = invx * QSCALE;
    const float sy = invy * QSCALE;

    // Swizzled destination for lane's float4 j (k0 = j*256 + lane*4):
    //   kb = j*2 + (lane>>5), q = (lane>>3)&3, b = (lane&7)*4
    const int p = row >> 4, r = row & 15;
    const int qs = (lane >> 3) & 3;
    const int bs = (lane & 7) * 4;
    #pragma unroll
    for (int j = 0; j < 4; ++j) {
        const int kb = j * 2 + (lane >> 5);
        const unsigned off = ((unsigned)(p * 32 + kb * 4 + qs) * 512 + r * 32 + bs) >> 2;
        int px = __builtin_amdgcn_cvt_pk_fp8_f32(xv[j].x * sx, xv[j].y * sx, 0, false);
        px     = __builtin_amdgcn_cvt_pk_fp8_f32(xv[j].z * sx, xv[j].w * sx, px, true);
        int py = __builtin_amdgcn_cvt_pk_fp8_f32(yv[j].x * sy, yv[j].y * sy, 0, false);
        py     = __builtin_amdgcn_cvt_pk_fp8_f32(yv[j].z * sy, yv[j].w * sy, py, true);
        xq[off] = (unsigned)px;
        yq[off] = (unsigned)py;
    }
    if (lane == 0) sdiag[row] = sxy * invx * invy;
}

// ---------------------------------------------------------------------------
// GEMM helpers
// ---------------------------------------------------------------------------
__device__ __forceinline__ i32x8_t ldfrag(const unsigned char* p) {
    const i32x4_t lo = *reinterpret_cast<const i32x4_t*>(p);
    const i32x4_t hi = *reinterpret_cast<const i32x4_t*>(p + 16);
    i32x8_t r;
    r[0] = lo[0]; r[1] = lo[1]; r[2] = lo[2]; r[3] = lo[3];
    r[4] = hi[0]; r[5] = hi[1]; r[6] = hi[2]; r[7] = hi[3];
    return r;
}

// One kb stage: prefetch next-stage B fragments, then A loads + 16 MFMAs for
// the current stage. bfC holds kb_cur's B-frags (loaded a stage earlier), so
// the compiler's waitcnt for the MFMAs is vmcnt(N>0) — no full drain.
__device__ __forceinline__ void stage(
    const unsigned char* Abase, const unsigned char* Bbase,
    int kb_cur, int kb_nxt,
    i32x8_t (&bfC)[4], i32x8_t (&bfN)[4], f32x4_t (&acc)[4][4])
{
    #pragma unroll
    for (int nt = 0; nt < 4; ++nt)
        bfN[nt] = ldfrag(Bbase + kb_nxt * 2048 + nt * 16384);
    #pragma unroll
    for (int mt = 0; mt < 4; ++mt) {
        const i32x8_t af = ldfrag(Abase + kb_cur * 2048 + mt * 16384);
        #pragma unroll
        for (int nt = 0; nt < 4; ++nt)
            acc[mt][nt] = __builtin_amdgcn_mfma_scale_f32_16x16x128_f8f6f4(
                af, bfC[nt], acc[mt][nt],
                0, 0,                       // cbsz=fp8(e4m3), blgp=fp8(e4m3)
                0, 0x7F7F7F7F,              // A scales: E8M0 127 = 2^0
                0, 0x7F7F7F7F);             // B scales: 2^0
    }
}

// ---------------------------------------------------------------------------
// Kernel 2: S' = 256 * xn*yn^T via MX-fp8 (unit scales), 128x128 tiles.
// No LDS/barriers (fragments direct from swizzled global, r7). New in r8:
//  (1) XCD-aware swizzle: 1-D grid, block id -> xcd=id&7 (HW round-robin);
//      XCD k owns block-rows [4k,4k+4), so its L2 working set is A strip
//      (512 KB) + B (4 MB) ~= its 4 MB L2 (r7: every XCD needed all 8 MB).
//  (2) B-fragment double-buffer across kb stages: the MFMA waitcnt becomes
//      vmcnt(N>0) instead of a per-stage drain.
// ---------------------------------------------------------------------------
__global__ __launch_bounds__(256) void gemm_exp_sums(
    const unsigned char* __restrict__ xq, const unsigned char* __restrict__ yq,
    float* __restrict__ rowsum, float* __restrict__ colsum)
{
    const int t    = threadIdx.x;
    const int lane = t & 63;
    const int wave = t >> 6;
    const int q    = lane >> 4;    // quad: selects 32B k-chunk
    const int l15  = lane & 15;

    const int id  = blockIdx.x;
    const int xcd = id & 7;
    const int jj  = id >> 3;           // 0..127 within XCD
    const int by  = xcd * 4 + (jj >> 5);
    const int bx  = jj & 31;

    const int R0 = by * 128;
    const int C0 = bx * 128;
    const int wRow = (wave >> 1) * 64;   // wave's 64x64 quadrant
    const int wCol = (wave & 1) * 64;

    f32x4_t acc[4][4];
    #pragma unroll
    for (int i = 0; i < 4; i++)
        #pragma unroll
        for (int j = 0; j < 4; j++)
            acc[i][j] = (f32x4_t){0.f, 0.f, 0.f, 0.f};

    // Panel bases; mt/nt step = 32*512 = 16384 B, kb step = 4*512 = 2048 B.
    const unsigned char* Abase =
        xq + (size_t)(((R0 + wRow) >> 4) * 32 + q) * 512 + l15 * 32;
    const unsigned char* Bbase =
        yq + (size_t)(((C0 + wCol) >> 4) * 32 + q) * 512 + l15 * 32;

    i32x8_t bf0[4], bf1[4];
    #pragma unroll
    for (int nt = 0; nt < 4; ++nt)
        bf0[nt] = ldfrag(Bbase + nt * 16384);    // kb=0 B-frags

    #pragma unroll 1
    for (int kb = 0; kb < 8; kb += 2) {
        stage(Abase, Bbase, kb,     kb + 1,       bf0, bf1, acc);
        stage(Abase, Bbase, kb + 1, (kb + 2) & 7, bf1, bf0, acc);
        // (kb=6 second stage redundantly prefetches kb=0 into bf0 — unused,
        //  16 harmless loads total.)
    }

    // Epilogue: E = exp(S/TAU); acc holds 256*S -> exp2(acc / (256*TAU*ln2)).
    const float kScale = (float)(1.0 / (256.0 * 0.07 * 0.6931471805599453));
    float csum[4] = {0.f, 0.f, 0.f, 0.f};
    #pragma unroll
    for (int mt = 0; mt < 4; ++mt) {
        float rsum[4] = {0.f, 0.f, 0.f, 0.f};
        #pragma unroll
        for (int nt = 0; nt < 4; ++nt) {
            #pragma unroll
            for (int r = 0; r < 4; ++r) {
                const float e = exp2f(acc[mt][nt][r] * kScale);
                rsum[r]  += e;
                csum[nt] += e;
            }
        }
        #pragma unroll
        for (int r = 0; r < 4; ++r) {
            float v = rsum[r];
            v += __shfl_xor(v, 1, 64);
            v += __shfl_xor(v, 2, 64);
            v += __shfl_xor(v, 4, 64);
            v += __shfl_xor(v, 8, 64);
            if (l15 == 0)
                atomicAdd(&rowsum[R0 + wRow + mt * 16 + q * 4 + r], v);
        }
    }
    #pragma unroll
    for (int nt = 0; nt < 4; ++nt) {
        float v = csum[nt];
        v += __shfl_xor(v, 16, 64);
        v += __shfl_xor(v, 32, 64);
        if (lane < 16)
            atomicAdd(&colsum[C0 + wCol + nt * 16 + l15], v);
    }
}

// ---------------------------------------------------------------------------
// Kernel 3: loss = -1/(2B) [ (2/TAU) * sum(sdiag)
//                            - sum(log(rowsum+extra)) - sum(log(colsum+extra)) ]
// Double accumulation (float tree-sum error would be too close to threshold).
// ---------------------------------------------------------------------------
__global__ __launch_bounds__(1024) void finalize(
    const float* __restrict__ rowsum, const float* __restrict__ colsum,
    const float* __restrict__ sdiag, float* __restrict__ out)
{
    const float extra = (float)(NB * 1e-6 + 1e-6);
    double local = 0.0;
    for (int i = threadIdx.x; i < NB; i += 1024) {
        local += (double)sdiag[i] * (2.0 / 0.07)
               - (double)logf(rowsum[i] + extra)
               - (double)logf(colsum[i] + extra);
    }
    #pragma unroll
    for (int off = 1; off < 64; off <<= 1)
        local += __shfl_xor(local, off, 64);
    __shared__ double dred[16];
    const int wave = threadIdx.x >> 6;
    if ((threadIdx.x & 63) == 0) dred[wave] = local;
    __syncthreads();
    if (threadIdx.x == 0) {
        double tot = 0.0;
        #pragma unroll
        for (int w = 0; w < 16; ++w) tot += dred[w];
        out[0] = (float)(tot * (-1.0 / (2.0 * NB)));
    }
}

// ---------------------------------------------------------------------------
extern "C" void kernel_launch(void* const* d_in, const int* in_sizes, int n_in,
                              void* d_out, int out_size, void* d_ws, size_t ws_size,
                              hipStream_t stream)
{
    const float* x = (const float*)d_in[0];
    const float* y = (const float*)d_in[1];
    float* out = (float*)d_out;

    char* ws = (char*)d_ws;
    unsigned char* xq = (unsigned char*)ws;                                 // 4 MB swizzled
    unsigned char* yq = (unsigned char*)(ws + (size_t)4 * 1024 * 1024);     // 4 MB swizzled
    float* rowsum = (float*)(ws + (size_t)8 * 1024 * 1024);                 // 16 KB
    float* colsum = rowsum + NB;                                            // 16 KB
    float* sdiag  = colsum + NB;                                            // 16 KB

    normalize_rows<<<NB / 4, 256, 0, stream>>>(x, y, (unsigned*)xq, (unsigned*)yq,
                                               sdiag, rowsum);

    gemm_exp_sums<<<1024, 256, 0, stream>>>(xq, yq, rowsum, colsum);

    finalize<<<1, 1024, 0, stream>>>(rowsum, colsum, sdiag, out);
}